// Round 1
// 62.382 us; speedup vs baseline: 1.2471x; 1.2471x over previous
//
#include <hip/hip_runtime.h>
#include <cstdint>
#include <cstddef>

#define N 8192
#define K 512
#define KP 128        // screened dims: MFMA GEMM only over first 128 of 512
#define NTILES 2080   // 64*65/2 upper-triangular 128x128 tiles

typedef __attribute__((ext_vector_type(8))) short short8;
typedef __attribute__((ext_vector_type(4))) float f32x4;

// ---------- helpers ----------

__device__ inline unsigned short f32_to_bf16_rne(float f) {
    unsigned int u = __float_as_uint(f);
    unsigned int r = u + 0x7FFFu + ((u >> 16) & 1u);
    return (unsigned short)(r >> 16);
}

__device__ inline float bf16_bits_to_f32(unsigned short h) {
    return __uint_as_float(((unsigned int)h) << 16);
}

__device__ inline void gload_lds16(const short* g, short* l) {
    __builtin_amdgcn_global_load_lds(
        (const __attribute__((address_space(1))) void*)g,
        (__attribute__((address_space(3))) void*)l,
        16 /*bytes*/, 0 /*offset*/, 0 /*aux*/);
}

__device__ inline void nt_store(float* p, f32x4 v) {
    __builtin_nontemporal_store(v, (f32x4*)p);
}

// ---------- kernel 1: bf16 convert (first 128 dims) + row norms ----------
// Per row: sq = ||x_bf16||^2 over all 512 dims, rn = ||x_bf16[128:512]|| (rest
// norm for the Cauchy-Schwarz screen). xb stores ONLY the first 128 dims
// (2 MB total -> L2-resident for the GEMM staging).
__global__ void prep_kernel(const float* __restrict__ x,
                            short* __restrict__ xb,
                            float* __restrict__ sq,
                            float* __restrict__ rn) {
    int tid  = threadIdx.x;
    int wave = tid >> 6;
    int lane = tid & 63;
    int row  = blockIdx.x * 4 + wave;

    const float* src = x + (size_t)row * K + lane * 8;
    float4 v0 = *(const float4*)(src);
    float4 v1 = *(const float4*)(src + 4);

    float vals[8] = {v0.x, v0.y, v0.z, v0.w, v1.x, v1.y, v1.z, v1.w};
    short8 packed;
    float ssum = 0.0f;
#pragma unroll
    for (int i = 0; i < 8; ++i) {
        unsigned short h = f32_to_bf16_rne(vals[i]);
        float f = bf16_bits_to_f32(h);
        ssum += f * f;
        packed[i] = (short)h;
    }
    // lanes 0..15 hold dims 0..127 -> those are the screened dims
    if (lane < KP / 8)
        *(short8*)(xb + (size_t)row * KP + lane * 8) = packed;
    float s128 = (lane < KP / 8) ? ssum : 0.0f;

#pragma unroll
    for (int off = 32; off > 0; off >>= 1) {
        ssum += __shfl_down(ssum, off, 64);
        s128 += __shfl_down(s128, off, 64);
    }
    if (lane == 0) {
        sq[row] = ssum;
        rn[row] = sqrtf(fmaxf(ssum - s128, 0.0f));
    }
}

// ---------- kernel 2: K=128 screening MFMA GEMM + interleaved zero-fill ----------
// Same verified triangular 128x128 / BK=32 / 2-phase structure, but the K-loop
// runs only 4 iterations (dims 0..127). The MFMA result dot128 feeds a RIGOROUS
// lower bound on d^2 (Cauchy-Schwarz on the remaining 384 dims):
//   d^2 >= sq_i + sq_j - 2*dot128 - 2*rn_i*rn_j
// If bound >= d2cut+margin, the zero written by the interleaved fill is correct
// (out < sigmoid(-5.5) < tolerance). Rare survivors take a cold exact-f32
// recompute of d^2 straight from x. Compute drops 4x and hides fully under the
// 256 MB output write (the real roofline).
__global__ __launch_bounds__(256) void gemm_dist_kernel(
        const short* __restrict__ xb,
        const float* __restrict__ sq,
        const float* __restrict__ rn,
        const float* __restrict__ x,
        const float* __restrict__ tptr,
        const float* __restrict__ thrptr,
        float* __restrict__ out) {
    __shared__ __align__(16) short smem[16384];        // 32 KB
    short* Abase = smem;                                // [2][128*32]
    short* Bbase = smem + 8192;                         // [2][128*32]

    // ---- triangular decode: block L -> (by, bx), by <= bx ----
    int L = blockIdx.x;
    float sf = sqrtf((float)(16641 - 8 * L));           // 129^2 = 16641
    int by = (int)((129.0f - sf) * 0.5f);
    by = by < 0 ? 0 : (by > 63 ? 63 : by);
    auto Tf = [](int n) { return n * 64 - (n * (n - 1)) / 2; };
    while (by > 0 && Tf(by) > L) --by;
    while (by < 63 && Tf(by + 1) <= L) ++by;
    int bx = by + (L - Tf(by));

    int tid  = threadIdx.x;
    int lane = tid & 63;
    int wave = tid >> 6;
    int wr = wave >> 1, wc = wave & 1;
    int fr = lane & 15, fsel = lane >> 4;

    int tileR = by * 128, tileC = bx * 128;
    bool diagBlk = (by == bx);

    f32x4 acc[4][4] = {};

    // ---- staging addressing (linear LDS dest, XOR-pre-swizzled global src) ----
    int srow = tid >> 2;                   // 0..63 (second issue: +64)
    int cl   = tid & 3;
    int gch  = cl ^ ((srow >> 1) & 3);
    const short* gA = xb + (size_t)(tileR + srow) * KP + gch * 8;
    const short* gB = xb + (size_t)(tileC + srow) * KP + gch * 8;
    int ldoff = srow * 32 + cl * 8;        // shorts

    // ---- fragment read offsets (swizzled) ----
    int swz = fsel ^ ((fr >> 1) & 3);      // logical k-chunk fsel at physical swz
    int ra[4], rb[4];
#pragma unroll
    for (int m = 0; m < 4; ++m) ra[m] = (wr * 64 + m * 16 + fr) * 32 + swz * 8;
#pragma unroll
    for (int n = 0; n < 4; ++n) rb[n] = (wc * 64 + n * 16 + fr) * 32 + swz * 8;

    auto STAGE = [&](int p, int kt) {
        short* Ad = Abase + p * 4096 + ldoff;
        short* Bd = Bbase + p * 4096 + ldoff;
        gload_lds16(gA + kt, Ad);
        gload_lds16(gA + (size_t)64 * KP + kt, Ad + 2048);
        gload_lds16(gB + kt, Bd);
        gload_lds16(gB + (size_t)64 * KP + kt, Bd + 2048);
    };

    // ---- zero-fill bases (each block owns its direct + mirror tiles) ----
    float* outD = out + (size_t)tileR * N + tileC;     // [128][128] at (tileR,tileC)
    float* outM = out + (size_t)tileC * N + tileR;     // [128][128] at (tileC,tileR)
    const f32x4 zero4 = {0.0f, 0.0f, 0.0f, 0.0f};

    // ---- 4-iteration K loop (dims 0..127) with interleaved zero-fill ----
    // Fill slices: t=0,1 cover the direct tile (rows 0..127), t=2,3 the mirror.
    // Branch is uniform per (t, j) -- no divergence. Nontemporal: 256 MB
    // streams once, keep it out of L2 so xb (2 MB) stays resident.
    STAGE(0, 0);
    __syncthreads();
    for (int t = 0; t < 4; ++t) {
        int cur = t & 1;
        if (t < 3) STAGE(cur ^ 1, (t + 1) * 32);

        {
            int rsub = tid >> 5;               // 0..7
            int c    = (tid & 31) << 2;
            if (t < 2) {
#pragma unroll
                for (int j = 0; j < 8; ++j) {
                    int r = t * 64 + j * 8 + rsub;
                    nt_store(outD + (size_t)r * N + c, zero4);
                }
            } else if (!diagBlk) {
#pragma unroll
                for (int j = 0; j < 8; ++j) {
                    int r = (t - 2) * 64 + j * 8 + rsub;
                    nt_store(outM + (size_t)r * N + c, zero4);
                }
            }
        }

        const short* Ab = Abase + cur * 4096;
        const short* Bb = Bbase + cur * 4096;
        short8 a[4], b[4];
#pragma unroll
        for (int m = 0; m < 4; ++m) a[m] = *(const short8*)(Ab + ra[m]);
#pragma unroll
        for (int n = 0; n < 4; ++n) b[n] = *(const short8*)(Bb + rb[n]);
#pragma unroll
        for (int m = 0; m < 4; ++m)
#pragma unroll
            for (int n = 0; n < 4; ++n)
                acc[m][n] = __builtin_amdgcn_mfma_f32_16x16x32_bf16(a[m], b[n], acc[m][n], 0, 0, 0);
        __syncthreads();   // drains vmcnt(0): staging AND this slice's fill stores
    }

    // ---- epilogue: screened exception patching ----
    float tv = tptr[0], th = thrptr[0];
    float Af = tv * 1.44269504f;           // t * log2(e)
    float Bf = th * Af;                    // thr * t * log2(e)
    float diagVal = __builtin_amdgcn_rcpf(1.0f + __builtin_amdgcn_exp2f(Bf));
    float d2cut;
    if (tv > 0.0f) {
        float s = 5.5f / tv - th;          // d >= s  =>  out < sigmoid(-5.5) < 1e-2
        d2cut = (s > 0.0f) ? s * s : -1e30f;
    } else {
        d2cut = 1e30f;                     // t <= 0: patch everything (slow, correct)
    }
    float d2cutm = d2cut + 8.0f;           // margin: covers f32/bf16 rounding slack

    float sqc[4], rnc[4];
#pragma unroll
    for (int n = 0; n < 4; ++n) {
        int gc = tileC + wc * 64 + n * 16 + fr;
        sqc[n] = sq[gc];
        rnc[n] = rn[gc];
    }

    int r0 = fsel * 4;
#pragma unroll
    for (int m = 0; m < 4; ++m) {
        int rloc  = wr * 64 + m * 16 + r0;
        int growb = tileR + rloc;
        float srs[4], rrs[4];
#pragma unroll
        for (int rr = 0; rr < 4; ++rr) {
            srs[rr] = sq[growb + rr];
            rrs[rr] = rn[growb + rr];
        }
#pragma unroll
        for (int n = 0; n < 4; ++n) {
            int gcol = tileC + wc * 64 + n * 16 + fr;
            bool need[4];
            bool anyq = false;
#pragma unroll
            for (int rr = 0; rr < 4; ++rr) {
                float g = acc[m][n][rr];   // dot over dims 0..127
                // rigorous lower bound on d^2 (Cauchy-Schwarz on dims 128..511)
                float bound = fmaf(-2.0f, g, srs[rr] + sqc[n])
                              - 2.0f * rrs[rr] * rnc[n];
                bool isd = diagBlk && (growb + rr == gcol);
                need[rr] = (bound < d2cutm) || isd;
                anyq |= need[rr];
            }
            if (__builtin_expect(__any((int)anyq), 0)) {
#pragma unroll
                for (int rr = 0; rr < 4; ++rr) {
                    if (need[rr]) {
                        int grow = growb + rr;
                        bool isd = diagBlk && (grow == gcol);
                        float r;
                        if (isd) {
                            r = diagVal;
                        } else {
                            // cold path: exact f32 distance straight from x
                            const float* xr = x + (size_t)grow * K;
                            const float* xc = x + (size_t)gcol * K;
                            float d2 = 0.0f;
#pragma unroll 4
                            for (int k2 = 0; k2 < K; k2 += 4) {
                                float4 a4 = *(const float4*)(xr + k2);
                                float4 b4 = *(const float4*)(xc + k2);
                                float dx = a4.x - b4.x, dy = a4.y - b4.y;
                                float dz = a4.z - b4.z, dw = a4.w - b4.w;
                                d2 = fmaf(dx, dx, d2);
                                d2 = fmaf(dy, dy, d2);
                                d2 = fmaf(dz, dz, d2);
                                d2 = fmaf(dw, dw, d2);
                            }
                            float d = __builtin_amdgcn_sqrtf(fmaxf(d2, 0.0f));
                            float e = __builtin_amdgcn_exp2f(fmaf(d, Af, Bf));
                            r = __builtin_amdgcn_rcpf(1.0f + e);
                        }
                        out[(size_t)grow * N + gcol] = r;
                        if (!diagBlk)
                            out[(size_t)gcol * N + grow] = r;
                    }
                }
            }
        }
    }
}

// ---------- launch ----------
extern "C" void kernel_launch(void* const* d_in, const int* in_sizes, int n_in,
                              void* d_out, int out_size, void* d_ws, size_t ws_size,
                              hipStream_t stream) {
    const float* x   = (const float*)d_in[0];
    const float* t   = (const float*)d_in[1];
    const float* thr = (const float*)d_in[2];
    float* out = (float*)d_out;

    short* xb = (short*)d_ws;                                           // 2 MB (N*128 bf16)
    float* sq = (float*)((char*)d_ws + (size_t)N * KP * sizeof(short)); // +32 KB
    float* rn = sq + N;                                                 // +32 KB

    prep_kernel<<<N / 4, 256, 0, stream>>>(x, xb, sq, rn);
    gemm_dist_kernel<<<NTILES, 256, 0, stream>>>(xb, sq, rn, x, t, thr, out);
}

// Round 2
// 61.919 us; speedup vs baseline: 1.2565x; 1.0075x over previous
//
#include <hip/hip_runtime.h>
#include <cstdint>
#include <cstddef>

#define N 8192
#define K 512
#define KP 128        // screened dims: MFMA GEMM only over first 128 of 512
#define NTILES 2080   // 64*65/2 upper-triangular 128x128 tiles

typedef __attribute__((ext_vector_type(8))) short short8;
typedef __attribute__((ext_vector_type(4))) float f32x4;

// ---------- helpers ----------

__device__ inline unsigned short f32_to_bf16_rne(float f) {
    unsigned int u = __float_as_uint(f);
    unsigned int r = u + 0x7FFFu + ((u >> 16) & 1u);
    return (unsigned short)(r >> 16);
}

__device__ inline float bf16_bits_to_f32(unsigned short h) {
    return __uint_as_float(((unsigned int)h) << 16);
}

__device__ inline void gload_lds16(const short* g, short* l) {
    __builtin_amdgcn_global_load_lds(
        (const __attribute__((address_space(1))) void*)g,
        (__attribute__((address_space(3))) void*)l,
        16 /*bytes*/, 0 /*offset*/, 0 /*aux*/);
}

__device__ inline void gload_lds4(const float* g, float* l) {
    __builtin_amdgcn_global_load_lds(
        (const __attribute__((address_space(1))) void*)g,
        (__attribute__((address_space(3))) void*)l,
        4 /*bytes*/, 0 /*offset*/, 0 /*aux*/);
}

__device__ inline void nt_store(float* p, f32x4 v) {
    __builtin_nontemporal_store(v, (f32x4*)p);
}

// ---------- kernel 1: bf16 convert (first 128 dims) + row norms ----------
__global__ void prep_kernel(const float* __restrict__ x,
                            short* __restrict__ xb,
                            float* __restrict__ sq,
                            float* __restrict__ rn) {
    int tid  = threadIdx.x;
    int wave = tid >> 6;
    int lane = tid & 63;
    int row  = blockIdx.x * 4 + wave;

    const float* src = x + (size_t)row * K + lane * 8;
    float4 v0 = *(const float4*)(src);
    float4 v1 = *(const float4*)(src + 4);

    float vals[8] = {v0.x, v0.y, v0.z, v0.w, v1.x, v1.y, v1.z, v1.w};
    short8 packed;
    float ssum = 0.0f;
#pragma unroll
    for (int i = 0; i < 8; ++i) {
        unsigned short h = f32_to_bf16_rne(vals[i]);
        float f = bf16_bits_to_f32(h);
        ssum += f * f;
        packed[i] = (short)h;
    }
    if (lane < KP / 8)
        *(short8*)(xb + (size_t)row * KP + lane * 8) = packed;
    float s128 = (lane < KP / 8) ? ssum : 0.0f;

#pragma unroll
    for (int off = 32; off > 0; off >>= 1) {
        ssum += __shfl_down(ssum, off, 64);
        s128 += __shfl_down(s128, off, 64);
    }
    if (lane == 0) {
        sq[row] = ssum;
        rn[row] = sqrtf(fmaxf(ssum - s128, 0.0f));
    }
}

// ---------- kernel 2: one-shot K=128 screening GEMM + streaming fill ----------
// Single-barrier-pair structure:
//   STAGE all 4 K-slabs (64 KB) + sq/rn -> LDS   (one vmcnt drain at sync#1)
//   issue ALL fill NT stores (fire-and-forget)
//   64 MFMAs from LDS (lgkm only -- hides the store drain)
//   sync#2: drains fills once, block-wide (patch stores ordered after fills)
//   screened epilogue: sq/rn from LDS (no VMEM on hot path -> no in-order
//   retirement stall behind the 32 outstanding fill stores)
__global__ __launch_bounds__(256) void gemm_dist_kernel(
        const short* __restrict__ xb,
        const float* __restrict__ sq,
        const float* __restrict__ rn,
        const float* __restrict__ x,
        const float* __restrict__ tptr,
        const float* __restrict__ thrptr,
        float* __restrict__ out) {
    __shared__ __align__(16) short smem[32768];        // A[4][128*32] + B[4][128*32] = 64 KB
    __shared__ __align__(16) float sqbuf[512];         // [0:128)=sq row, [128:256)=sq col,
                                                       // [256:384)=rn row, [384:512)=rn col
    short* Abase = smem;
    short* Bbase = smem + 16384;

    // ---- triangular decode: block L -> (by, bx), by <= bx ----
    int L = blockIdx.x;
    float sf = sqrtf((float)(16641 - 8 * L));           // 129^2 = 16641
    int by = (int)((129.0f - sf) * 0.5f);
    by = by < 0 ? 0 : (by > 63 ? 63 : by);
    auto Tf = [](int n) { return n * 64 - (n * (n - 1)) / 2; };
    while (by > 0 && Tf(by) > L) --by;
    while (by < 63 && Tf(by + 1) <= L) ++by;
    int bx = by + (L - Tf(by));

    int tid  = threadIdx.x;
    int lane = tid & 63;
    int wave = tid >> 6;
    int wr = wave >> 1, wc = wave & 1;
    int fr = lane & 15, fsel = lane >> 4;

    int tileR = by * 128, tileC = bx * 128;
    bool diagBlk = (by == bx);

    f32x4 acc[4][4] = {};

    // ---- staging addressing (linear LDS dest, XOR-pre-swizzled global src) ----
    int srow = tid >> 2;                   // 0..63 (second issue: +64)
    int cl   = tid & 3;
    int gch  = cl ^ ((srow >> 1) & 3);
    const short* gA = xb + (size_t)(tileR + srow) * KP + gch * 8;
    const short* gB = xb + (size_t)(tileC + srow) * KP + gch * 8;
    int ldoff = srow * 32 + cl * 8;        // shorts

    // ---- fragment read offsets (swizzled) ----
    int swz = fsel ^ ((fr >> 1) & 3);
    int ra[4], rb[4];
#pragma unroll
    for (int m = 0; m < 4; ++m) ra[m] = (wr * 64 + m * 16 + fr) * 32 + swz * 8;
#pragma unroll
    for (int n = 0; n < 4; ++n) rb[n] = (wc * 64 + n * 16 + fr) * 32 + swz * 8;

    // ---- stage all 4 K-slabs ----
#pragma unroll
    for (int p = 0; p < 4; ++p) {
        short* Ad = Abase + p * 4096 + ldoff;
        short* Bd = Bbase + p * 4096 + ldoff;
        int kt = p * 32;
        gload_lds16(gA + kt, Ad);
        gload_lds16(gA + (size_t)64 * KP + kt, Ad + 2048);
        gload_lds16(gB + kt, Bd);
        gload_lds16(gB + (size_t)64 * KP + kt, Bd + 2048);
    }
    // ---- stage sq/rn for this tile's rows+cols into LDS ----
#pragma unroll
    for (int i = 0; i < 2; ++i) {
        int idx = tid + i * 256;
        int j = idx & 127;
        const float* src;
        if (idx < 128)      src = sq + tileR + j;
        else if (idx < 256) src = sq + tileC + j;
        else if (idx < 384) src = rn + tileR + j;
        else                src = rn + tileC + j;
        gload_lds4(src, &sqbuf[idx]);
    }
    __syncthreads();   // sync#1: staging complete

    // ---- issue ALL zero-fill NT stores (fire-and-forget) ----
    float* outD = out + (size_t)tileR * N + tileC;
    float* outM = out + (size_t)tileC * N + tileR;
    const f32x4 zero4 = {0.0f, 0.0f, 0.0f, 0.0f};
    {
        int rsub = tid >> 5;               // 0..7
        int c    = (tid & 31) << 2;
#pragma unroll
        for (int j = 0; j < 16; ++j)
            nt_store(outD + (size_t)(j * 8 + rsub) * N + c, zero4);
        if (!diagBlk) {
#pragma unroll
            for (int j = 0; j < 16; ++j)
                nt_store(outM + (size_t)(j * 8 + rsub) * N + c, zero4);
        }
    }

    // ---- 64 MFMAs from LDS (pure lgkm work under the store drain) ----
#pragma unroll
    for (int p = 0; p < 4; ++p) {
        const short* Ab = Abase + p * 4096;
        const short* Bb = Bbase + p * 4096;
        short8 a[4], b[4];
#pragma unroll
        for (int m = 0; m < 4; ++m) a[m] = *(const short8*)(Ab + ra[m]);
#pragma unroll
        for (int n = 0; n < 4; ++n) b[n] = *(const short8*)(Bb + rb[n]);
#pragma unroll
        for (int m = 0; m < 4; ++m)
#pragma unroll
            for (int n = 0; n < 4; ++n)
                acc[m][n] = __builtin_amdgcn_mfma_f32_16x16x32_bf16(a[m], b[n], acc[m][n], 0, 0, 0);
    }
    __syncthreads();   // sync#2: drains all fill stores block-wide
                       // (patch stores below are strictly ordered after fills)

    // ---- screened epilogue (sq/rn from LDS; no hot-path VMEM) ----
    float tv = tptr[0], th = thrptr[0];
    float Af = tv * 1.44269504f;           // t * log2(e)
    float Bf = th * Af;                    // thr * t * log2(e)
    float diagVal = __builtin_amdgcn_rcpf(1.0f + __builtin_amdgcn_exp2f(Bf));
    float d2cut;
    if (tv > 0.0f) {
        float s = 5.5f / tv - th;          // d >= s  =>  out < sigmoid(-5.5) < 1e-2
        d2cut = (s > 0.0f) ? s * s : -1e30f;
    } else {
        d2cut = 1e30f;                     // t <= 0: patch everything (slow, correct)
    }
    float d2cutm = d2cut + 8.0f;           // margin: f32/bf16 rounding slack

    float sqc[4], rnc[4];
#pragma unroll
    for (int n = 0; n < 4; ++n) {
        int jc = wc * 64 + n * 16 + fr;
        sqc[n] = sqbuf[128 + jc];
        rnc[n] = sqbuf[384 + jc];
    }

    int r0 = fsel * 4;
#pragma unroll
    for (int m = 0; m < 4; ++m) {
        int rloc  = wr * 64 + m * 16 + r0;
        int growb = tileR + rloc;
        float srs[4], rrs[4];
#pragma unroll
        for (int rr = 0; rr < 4; ++rr) {
            srs[rr] = sqbuf[rloc + rr];
            rrs[rr] = sqbuf[256 + rloc + rr];
        }
#pragma unroll
        for (int n = 0; n < 4; ++n) {
            int gcol = tileC + wc * 64 + n * 16 + fr;
            bool need[4];
            bool anyq = false;
#pragma unroll
            for (int rr = 0; rr < 4; ++rr) {
                float g = acc[m][n][rr];   // dot over dims 0..127
                // rigorous lower bound on d^2 (Cauchy-Schwarz on dims 128..511)
                float bound = fmaf(-2.0f, g, srs[rr] + sqc[n])
                              - 2.0f * rrs[rr] * rnc[n];
                bool isd = diagBlk && (growb + rr == gcol);
                need[rr] = (bound < d2cutm) || isd;
                anyq |= need[rr];
            }
            if (__builtin_expect(__any((int)anyq), 0)) {
#pragma unroll
                for (int rr = 0; rr < 4; ++rr) {
                    if (need[rr]) {
                        int grow = growb + rr;
                        bool isd = diagBlk && (grow == gcol);
                        float r;
                        if (isd) {
                            r = diagVal;
                        } else {
                            // cold path: exact f32 distance straight from x
                            const float* xr = x + (size_t)grow * K;
                            const float* xc = x + (size_t)gcol * K;
                            float d2 = 0.0f;
#pragma unroll 4
                            for (int k2 = 0; k2 < K; k2 += 4) {
                                float4 a4 = *(const float4*)(xr + k2);
                                float4 b4 = *(const float4*)(xc + k2);
                                float dx = a4.x - b4.x, dy = a4.y - b4.y;
                                float dz = a4.z - b4.z, dw = a4.w - b4.w;
                                d2 = fmaf(dx, dx, d2);
                                d2 = fmaf(dy, dy, d2);
                                d2 = fmaf(dz, dz, d2);
                                d2 = fmaf(dw, dw, d2);
                            }
                            float d = __builtin_amdgcn_sqrtf(fmaxf(d2, 0.0f));
                            float e = __builtin_amdgcn_exp2f(fmaf(d, Af, Bf));
                            r = __builtin_amdgcn_rcpf(1.0f + e);
                        }
                        out[(size_t)grow * N + gcol] = r;
                        if (!diagBlk)
                            out[(size_t)gcol * N + grow] = r;
                    }
                }
            }
        }
    }
}

// ---------- launch ----------
extern "C" void kernel_launch(void* const* d_in, const int* in_sizes, int n_in,
                              void* d_out, int out_size, void* d_ws, size_t ws_size,
                              hipStream_t stream) {
    const float* x   = (const float*)d_in[0];
    const float* t   = (const float*)d_in[1];
    const float* thr = (const float*)d_in[2];
    float* out = (float*)d_out;

    short* xb = (short*)d_ws;                                           // 2 MB (N*128 bf16)
    float* sq = (float*)((char*)d_ws + (size_t)N * KP * sizeof(short)); // +32 KB
    float* rn = sq + N;                                                 // +32 KB

    prep_kernel<<<N / 4, 256, 0, stream>>>(x, xb, sq, rn);
    gemm_dist_kernel<<<NTILES, 256, 0, stream>>>(xb, sq, rn, x, t, thr, out);
}

// Round 3
// 61.000 us; speedup vs baseline: 1.2754x; 1.0151x over previous
//
#include <hip/hip_runtime.h>
#include <cstdint>
#include <cstddef>

#define N 8192
#define K 512
#define KP 64         // screened dims: MFMA GEMM only over first 64 of 512
#define NTILES 2080   // 64*65/2 upper-triangular 128x128 tiles

typedef __attribute__((ext_vector_type(8))) short short8;
typedef __attribute__((ext_vector_type(4))) float f32x4;

// ---------- helpers ----------

__device__ inline unsigned short f32_to_bf16_rne(float f) {
    unsigned int u = __float_as_uint(f);
    unsigned int r = u + 0x7FFFu + ((u >> 16) & 1u);
    return (unsigned short)(r >> 16);
}

__device__ inline float bf16_bits_to_f32(unsigned short h) {
    return __uint_as_float(((unsigned int)h) << 16);
}

__device__ inline void gload_lds16(const short* g, short* l) {
    __builtin_amdgcn_global_load_lds(
        (const __attribute__((address_space(1))) void*)g,
        (__attribute__((address_space(3))) void*)l,
        16 /*bytes*/, 0 /*offset*/, 0 /*aux*/);
}

__device__ inline void gload_lds4(const float* g, float* l) {
    __builtin_amdgcn_global_load_lds(
        (const __attribute__((address_space(1))) void*)g,
        (__attribute__((address_space(3))) void*)l,
        4 /*bytes*/, 0 /*offset*/, 0 /*aux*/);
}

__device__ inline void nt_store(float* p, f32x4 v) {
    __builtin_nontemporal_store(v, (f32x4*)p);
}

// ---------- kernel 1: bf16 convert (first 64 dims) + row norms ----------
// sq = ||x_bf16||^2 over all 512 dims; rn = ||x_bf16[64:512]|| (rest norm for
// the Cauchy-Schwarz screen). xb stores only dims 0..63 (1 MB total).
__global__ void prep_kernel(const float* __restrict__ x,
                            short* __restrict__ xb,
                            float* __restrict__ sq,
                            float* __restrict__ rn) {
    int tid  = threadIdx.x;
    int wave = tid >> 6;
    int lane = tid & 63;
    int row  = blockIdx.x * 4 + wave;

    const float* src = x + (size_t)row * K + lane * 8;
    float4 v0 = *(const float4*)(src);
    float4 v1 = *(const float4*)(src + 4);

    float vals[8] = {v0.x, v0.y, v0.z, v0.w, v1.x, v1.y, v1.z, v1.w};
    short8 packed;
    float ssum = 0.0f;
#pragma unroll
    for (int i = 0; i < 8; ++i) {
        unsigned short h = f32_to_bf16_rne(vals[i]);
        float f = bf16_bits_to_f32(h);
        ssum += f * f;
        packed[i] = (short)h;
    }
    if (lane < KP / 8)
        *(short8*)(xb + (size_t)row * KP + lane * 8) = packed;
    float shead = (lane < KP / 8) ? ssum : 0.0f;

#pragma unroll
    for (int off = 32; off > 0; off >>= 1) {
        ssum  += __shfl_down(ssum, off, 64);
        shead += __shfl_down(shead, off, 64);
    }
    if (lane == 0) {
        sq[row] = ssum;
        rn[row] = sqrtf(fmaxf(ssum - shead, 0.0f));
    }
}

// ---------- kernel 2: K=64 screening GEMM + fire-and-forget streaming fill ----------
// Structure per block (single shot, NO post-fill drain):
//   stage A/B (32 KB) + sq/rn -> LDS; __syncthreads (drains own stage loads only)
//   32 MFMAs from LDS
//   issue ALL fill NT stores (diagVal merged in-fill for diag blocks) -- these
//   are NEVER waited on: vmcnt is per-wave, s_endpgm may retire with stores in
//   flight, so back-pressure alone throttles issue at HBM rate and the write
//   pipe never empties across block boundaries.
//   screen: rigorous C-S lower bound on d^2; RARE survivors take a wave-local
//   s_waitcnt vmcnt(0) (own fills only -- quadrant ownership makes fill and
//   patch the same wave) then exact-f32 recompute + patch store.
__global__ __launch_bounds__(256) void gemm_dist_kernel(
        const short* __restrict__ xb,
        const float* __restrict__ sq,
        const float* __restrict__ rn,
        const float* __restrict__ x,
        const float* __restrict__ tptr,
        const float* __restrict__ thrptr,
        float* __restrict__ out) {
    __shared__ __align__(16) short smem[16384];        // A[2][128*32] + B[2][128*32] = 32 KB
    __shared__ __align__(16) float sqbuf[512];         // sqR, sqC, rnR, rnC (128 each)
    short* Abase = smem;
    short* Bbase = smem + 8192;

    // ---- triangular decode: block L -> (by, bx), by <= bx ----
    int L = blockIdx.x;
    float sf = sqrtf((float)(16641 - 8 * L));           // 129^2 = 16641
    int by = (int)((129.0f - sf) * 0.5f);
    by = by < 0 ? 0 : (by > 63 ? 63 : by);
    auto Tf = [](int n) { return n * 64 - (n * (n - 1)) / 2; };
    while (by > 0 && Tf(by) > L) --by;
    while (by < 63 && Tf(by + 1) <= L) ++by;
    int bx = by + (L - Tf(by));

    int tid  = threadIdx.x;
    int lane = tid & 63;
    int wave = tid >> 6;
    int wr = wave >> 1, wc = wave & 1;
    int fr = lane & 15, fsel = lane >> 4;

    int tileR = by * 128, tileC = bx * 128;
    bool diagBlk = (by == bx);

    // scalar params early (retire by sync#1)
    float tv = tptr[0], th = thrptr[0];

    f32x4 acc[4][4] = {};

    // ---- staging addressing (linear LDS dest, XOR-pre-swizzled global src) ----
    int srow = tid >> 2;                   // 0..63 (second issue: +64)
    int cl   = tid & 3;
    int gch  = cl ^ ((srow >> 1) & 3);
    const short* gA = xb + (size_t)(tileR + srow) * KP + gch * 8;
    const short* gB = xb + (size_t)(tileC + srow) * KP + gch * 8;
    int ldoff = srow * 32 + cl * 8;        // shorts

    // ---- fragment read offsets (swizzled) ----
    int swz = fsel ^ ((fr >> 1) & 3);
    int ra[4], rb[4];
#pragma unroll
    for (int m = 0; m < 4; ++m) ra[m] = (wr * 64 + m * 16 + fr) * 32 + swz * 8;
#pragma unroll
    for (int n = 0; n < 4; ++n) rb[n] = (wc * 64 + n * 16 + fr) * 32 + swz * 8;

    // ---- stage both K-slabs (dims 0..63) ----
#pragma unroll
    for (int p = 0; p < 2; ++p) {
        short* Ad = Abase + p * 4096 + ldoff;
        short* Bd = Bbase + p * 4096 + ldoff;
        int kt = p * 32;
        gload_lds16(gA + kt, Ad);
        gload_lds16(gA + (size_t)64 * KP + kt, Ad + 2048);
        gload_lds16(gB + kt, Bd);
        gload_lds16(gB + (size_t)64 * KP + kt, Bd + 2048);
    }
    // ---- stage sq/rn for this tile's rows+cols into LDS ----
#pragma unroll
    for (int i = 0; i < 2; ++i) {
        int idx = tid + i * 256;
        int j = idx & 127;
        const float* src;
        if (idx < 128)      src = sq + tileR + j;
        else if (idx < 256) src = sq + tileC + j;
        else if (idx < 384) src = rn + tileR + j;
        else                src = rn + tileC + j;
        gload_lds4(src, &sqbuf[idx]);
    }
    __syncthreads();   // drains own stage loads; no fill stores exist yet

    // ---- 32 MFMAs from LDS ----
#pragma unroll
    for (int p = 0; p < 2; ++p) {
        const short* Ab = Abase + p * 4096;
        const short* Bb = Bbase + p * 4096;
        short8 a[4], b[4];
#pragma unroll
        for (int m = 0; m < 4; ++m) a[m] = *(const short8*)(Ab + ra[m]);
#pragma unroll
        for (int n = 0; n < 4; ++n) b[n] = *(const short8*)(Bb + rb[n]);
#pragma unroll
        for (int m = 0; m < 4; ++m)
#pragma unroll
            for (int n = 0; n < 4; ++n)
                acc[m][n] = __builtin_amdgcn_mfma_f32_16x16x32_bf16(a[m], b[n], acc[m][n], 0, 0, 0);
    }

    // ---- derived params ----
    float Af = tv * 1.44269504f;           // t * log2(e)
    float Bf = th * Af;                    // thr * t * log2(e)
    float diagVal = __builtin_amdgcn_rcpf(1.0f + __builtin_amdgcn_exp2f(Bf));
    float d2cut;
    if (tv > 0.0f) {
        float s = 5.5f / tv - th;          // d >= s  =>  out < sigmoid(-5.5) < 1e-2
        d2cut = (s > 0.0f) ? s * s : -1e30f;
    } else {
        d2cut = 1e30f;                     // t <= 0: patch everything (slow, correct)
    }
    float d2cutm = d2cut + 8.0f;           // margin: f32/bf16 rounding slack

    // ---- fire-and-forget fills: wave (wr,wc) owns direct quadrant
    //      [wr*64,wc*64] and mirror quadrant [wc*64,wr*64] ----
    float* outD = out + (size_t)tileR * N + tileC;
    float* outM = out + (size_t)tileC * N + tileR;
    const f32x4 zero4 = {0.0f, 0.0f, 0.0f, 0.0f};
    {
        int frow = lane >> 4;              // 0..3
        int fcol = (lane & 15) << 2;       // 0..60
        float* qD = outD + (size_t)(wr * 64) * N + wc * 64;
        bool dg = diagBlk && (wr == wc);
        if (dg) {
#pragma unroll
            for (int j = 0; j < 16; ++j) {
                f32x4 v = zero4;
                // diag entry of row j*4+frow sits at col j*4+frow:
                // lane (l&15)==j holds it, component frow
                if ((lane & 15) == j) v[0] = (frow == 0) ? diagVal : 0.0f;
                if ((lane & 15) == j && frow == 1) v[1] = diagVal;
                if ((lane & 15) == j && frow == 2) v[2] = diagVal;
                if ((lane & 15) == j && frow == 3) v[3] = diagVal;
                nt_store(qD + (size_t)(j * 4 + frow) * N + fcol, v);
            }
        } else {
#pragma unroll
            for (int j = 0; j < 16; ++j)
                nt_store(qD + (size_t)(j * 4 + frow) * N + fcol, zero4);
        }
        if (!diagBlk) {
            float* qM = outM + (size_t)(wc * 64) * N + wr * 64;
#pragma unroll
            for (int j = 0; j < 16; ++j)
                nt_store(qM + (size_t)(j * 4 + frow) * N + fcol, zero4);
        }
    }

    // ---- screen pass 1: does ANY entry in this wave survive? ----
    float sqc[4], rnc[4];
#pragma unroll
    for (int n = 0; n < 4; ++n) {
        int jc = wc * 64 + n * 16 + fr;
        sqc[n] = sqbuf[128 + jc];
        rnc[n] = sqbuf[384 + jc];
    }
    int r0 = fsel * 4;
    bool anyAll = false;
#pragma unroll
    for (int m = 0; m < 4; ++m) {
        int rloc  = wr * 64 + m * 16 + r0;
        int growb = tileR + rloc;
#pragma unroll
        for (int n = 0; n < 4; ++n) {
            int gcol = tileC + wc * 64 + n * 16 + fr;
#pragma unroll
            for (int rr = 0; rr < 4; ++rr) {
                float g = acc[m][n][rr];   // dot over dims 0..63
                float bound = fmaf(-2.0f, g, sqbuf[rloc + rr] + sqc[n])
                              - 2.0f * sqbuf[256 + rloc + rr] * rnc[n];
                bool isd = diagBlk && (growb + rr == gcol);   // diag: already in fill
                anyAll |= (bound < d2cutm) && !isd;
            }
        }
    }

    // ---- rare patch path: wave-local ordering (own fills only) ----
    if (__builtin_expect(__any((int)anyAll), 0)) {
        asm volatile("s_waitcnt vmcnt(0)" ::: "memory");   // own fills retired
#pragma unroll
        for (int m = 0; m < 4; ++m) {
            int rloc  = wr * 64 + m * 16 + r0;
            int growb = tileR + rloc;
#pragma unroll
            for (int n = 0; n < 4; ++n) {
                int gcol = tileC + wc * 64 + n * 16 + fr;
#pragma unroll
                for (int rr = 0; rr < 4; ++rr) {
                    float g = acc[m][n][rr];
                    float bound = fmaf(-2.0f, g, sqbuf[rloc + rr] + sqc[n])
                                  - 2.0f * sqbuf[256 + rloc + rr] * rnc[n];
                    int grow = growb + rr;
                    bool isd = diagBlk && (grow == gcol);
                    if ((bound < d2cutm) && !isd) {
                        // exact f32 distance straight from x
                        const float* xr = x + (size_t)grow * K;
                        const float* xc = x + (size_t)gcol * K;
                        float d2 = 0.0f;
#pragma unroll 4
                        for (int k2 = 0; k2 < K; k2 += 4) {
                            float4 a4 = *(const float4*)(xr + k2);
                            float4 b4 = *(const float4*)(xc + k2);
                            float dx = a4.x - b4.x, dy = a4.y - b4.y;
                            float dz = a4.z - b4.z, dw = a4.w - b4.w;
                            d2 = fmaf(dx, dx, d2);
                            d2 = fmaf(dy, dy, d2);
                            d2 = fmaf(dz, dz, d2);
                            d2 = fmaf(dw, dw, d2);
                        }
                        float d = __builtin_amdgcn_sqrtf(fmaxf(d2, 0.0f));
                        float e = __builtin_amdgcn_exp2f(fmaf(d, Af, Bf));
                        float r = __builtin_amdgcn_rcpf(1.0f + e);
                        out[(size_t)grow * N + gcol] = r;
                        if (!diagBlk)
                            out[(size_t)gcol * N + grow] = r;
                    }
                }
            }
        }
    }
}

// ---------- launch ----------
extern "C" void kernel_launch(void* const* d_in, const int* in_sizes, int n_in,
                              void* d_out, int out_size, void* d_ws, size_t ws_size,
                              hipStream_t stream) {
    const float* x   = (const float*)d_in[0];
    const float* t   = (const float*)d_in[1];
    const float* thr = (const float*)d_in[2];
    float* out = (float*)d_out;

    short* xb = (short*)d_ws;                                           // 1 MB (N*64 bf16)
    float* sq = (float*)((char*)d_ws + (size_t)N * KP * sizeof(short)); // +32 KB
    float* rn = sq + N;                                                 // +32 KB

    prep_kernel<<<N / 4, 256, 0, stream>>>(x, xb, sq, rn);
    gemm_dist_kernel<<<NTILES, 256, 0, stream>>>(xb, sq, rn, x, t, thr, out);
}